// Round 2
// baseline (271.213 us; speedup 1.0000x reference)
//
#include <hip/hip_runtime.h>
#include <stdint.h>
#include <math.h>

constexpr int BROWS = 256;
constexpr int VCOLS = 128000;
constexpr int NTHREADS = 1024;
constexpr int NWAVES = NTHREADS / 64;
constexpr int NV4 = VCOLS / 4;          // 32000 float4 elements per row

__device__ __forceinline__ uint32_t rotl(uint32_t x, int r) {
  return (x << r) | (x >> (32 - r));
}

struct U2 { uint32_t a, b; };

// Threefry-2x32 with key (0,1)  [jax.random.key(1)]
// ks = [0, 1, 0^1^0x1BD11BDA = 0x1BD11BDB]
// Partitionable path (JAX >= 0.5 default): counter = (hi=0, lo=i),
// output bits = out0 ^ out1.
__device__ __forceinline__ U2 tf2x32(uint32_t c0, uint32_t c1) {
  uint32_t x0 = c0;          // + ks[0] == 0
  uint32_t x1 = c1 + 1u;     // + ks[1] == 1
#define R4(r0,r1,r2,r3) \
  x0 += x1; x1 = rotl(x1, r0); x1 ^= x0; \
  x0 += x1; x1 = rotl(x1, r1); x1 ^= x0; \
  x0 += x1; x1 = rotl(x1, r2); x1 ^= x0; \
  x0 += x1; x1 = rotl(x1, r3); x1 ^= x0;
  R4(13,15,26,6)
  x0 += 1u;            x1 += 0x1BD11BDBu + 1u;   // ks[1], ks[2]+1
  R4(17,29,16,24)
  x0 += 0x1BD11BDBu;   x1 += 0u + 2u;            // ks[2], ks[0]+2
  R4(13,15,26,6)
  /* x0 += ks[0]==0 */ x1 += 1u + 3u;            // ks[0], ks[1]+3
  R4(17,29,16,24)
  x0 += 1u;            x1 += 0x1BD11BDBu + 4u;   // ks[1], ks[2]+4
  R4(13,15,26,6)
  x0 += 0x1BD11BDBu;   x1 += 0u + 5u;            // ks[2], ks[0]+5
#undef R4
  return {x0, x1};
}

// max with first-index tiebreak; NaN treated as greater than everything
// (numpy/jax argmax semantics)
__device__ __forceinline__ void combineMax(float v, int i, float &bv, int &bi) {
  bool vn = isnan(v), bn = isnan(bv);
  bool take = vn ? (!bn || i < bi)
                 : (!bn && (v > bv || (v == bv && i < bi)));
  if (take) { bv = v; bi = i; }
}

__device__ __forceinline__ void waveReduceMax(float &bv, int &bi) {
  #pragma unroll
  for (int off = 32; off > 0; off >>= 1) {
    float ov = __shfl_xor(bv, off, 64);
    int   oi = __shfl_xor(bi, off, 64);
    combineMax(ov, oi, bv, bi);
  }
}

extern "C" __global__ void __launch_bounds__(NTHREADS)
sampler_kernel(const float* __restrict__ logits,
               const float* __restrict__ temps,
               int* __restrict__ out)
{
  const int row = blockIdx.x;
  const int tid = threadIdx.x;
  const int wid = tid >> 6, lane = tid & 63;
  const float* lrow = logits + (size_t)row * VCOLS;
  const float t = temps[row];
  const float safe_t = (t == 0.0f) ? 1.0f : t;

  __shared__ float s_v[NWAVES];
  __shared__ int   s_i[NWAVES];
  __shared__ float s_m;
  __shared__ float s_z;
  __shared__ int   s_greedy;

  // ---------------- Phase 1: row max of x = l/safe_t, first-index argmax ----
  float bv = -INFINITY; int bi = 0x7FFFFFFF;
  for (int vv = tid; vv < NV4; vv += NTHREADS) {
    float4 l4 = reinterpret_cast<const float4*>(lrow)[vv];
    int v0 = vv * 4;
    combineMax(l4.x / safe_t, v0 + 0, bv, bi);
    combineMax(l4.y / safe_t, v0 + 1, bv, bi);
    combineMax(l4.z / safe_t, v0 + 2, bv, bi);
    combineMax(l4.w / safe_t, v0 + 3, bv, bi);
  }
  waveReduceMax(bv, bi);
  if (lane == 0) { s_v[wid] = bv; s_i[wid] = bi; }
  __syncthreads();
  if (tid == 0) {
    float mv = s_v[0]; int mi = s_i[0];
    for (int w = 1; w < NWAVES; ++w) combineMax(s_v[w], s_i[w], mv, mi);
    s_m = mv; s_greedy = mi;
  }
  __syncthreads();
  const float m = s_m;

  // ---------------- Phase 2: Z = sum expf(x - m) ----------------------------
  float zsum = 0.0f;
  for (int vv = tid; vv < NV4; vv += NTHREADS) {
    float4 l4 = reinterpret_cast<const float4*>(lrow)[vv];
    zsum += expf(l4.x / safe_t - m);
    zsum += expf(l4.y / safe_t - m);
    zsum += expf(l4.z / safe_t - m);
    zsum += expf(l4.w / safe_t - m);
  }
  #pragma unroll
  for (int off = 32; off > 0; off >>= 1) zsum += __shfl_xor(zsum, off, 64);
  if (lane == 0) s_v[wid] = zsum;
  __syncthreads();
  if (tid == 0) {
    float z = 0.0f;
    for (int w = 0; w < NWAVES; ++w) z += s_v[w];
    s_z = z;
  }
  __syncthreads();
  const float Z = s_z;

  // ---------------- Phase 3: argmax of (exp(d)/Z) / noise -------------------
  // Partitionable threefry: element flat index i -> counter (0, i),
  // bits = out0 ^ out1. u = bitcast((bits>>9)|0x3f800000)-1; noise=-log1p(-u).
  const uint32_t flatbase = (uint32_t)row * (uint32_t)VCOLS;
  float rv = -INFINITY; int ri = 0x7FFFFFFF;
  for (int vv = tid; vv < NV4; vv += NTHREADS) {
    float4 l4 = reinterpret_cast<const float4*>(lrow)[vv];
    int v0 = vv * 4;
    float lx[4] = {l4.x, l4.y, l4.z, l4.w};
    #pragma unroll
    for (int k = 0; k < 4; ++k) {
      uint32_t i = flatbase + (uint32_t)(v0 + k);
      U2 o = tf2x32(0u, i);
      uint32_t bits = o.a ^ o.b;
      float f = __uint_as_float((bits >> 9) | 0x3F800000u);
      float u = f - 1.0f;
      float noise = -log1pf(-u);                 // +0.0 when bits>>9==0
      float p = expf(lx[k] / safe_t - m) / Z;    // softmax prob (0 on underflow)
      float ratio = p / noise;                   // inf / NaN semantics preserved
      combineMax(ratio, v0 + k, rv, ri);
    }
  }
  waveReduceMax(rv, ri);
  if (lane == 0) { s_v[wid] = rv; s_i[wid] = ri; }
  __syncthreads();
  if (tid == 0) {
    float fv = s_v[0]; int fi = s_i[0];
    for (int w = 1; w < NWAVES; ++w) combineMax(s_v[w], s_i[w], fv, fi);
    out[row] = (t == 0.0f) ? s_greedy : fi;
  }
}

extern "C" void kernel_launch(void* const* d_in, const int* in_sizes, int n_in,
                              void* d_out, int out_size, void* d_ws, size_t ws_size,
                              hipStream_t stream) {
  const float* logits = (const float*)d_in[0];
  const float* temps  = (const float*)d_in[1];
  int* out = (int*)d_out;
  sampler_kernel<<<BROWS, NTHREADS, 0, stream>>>(logits, temps, out);
}

// Round 3
// 171.448 us; speedup vs baseline: 1.5819x; 1.5819x over previous
//
#include <hip/hip_runtime.h>
#include <stdint.h>
#include <math.h>

constexpr int BROWS = 256;
constexpr int VCOLS = 128000;
constexpr int NQ    = 4;                 // quarter-rows
constexpr int QCOLS = VCOLS / NQ;        // 32000
constexpr int QV4   = QCOLS / 4;         // 8000 float4 per quarter
constexpr int NBLK  = BROWS * NQ;        // 1024 blocks
constexpr int NTHR  = 512;               // 8 waves per block

// ---------- sortable float <-> uint mapping (order-isomorphic) --------------
__device__ __forceinline__ uint32_t fmap(float v) {
  uint32_t b = __float_as_uint(v);
  return b ^ (uint32_t)(((int32_t)b >> 31) | 0x80000000);
}
__device__ __forceinline__ float funmap(uint32_t s) {
  uint32_t b = s ^ (uint32_t)(((~(int32_t)s) >> 31) | 0x80000000);
  return __uint_as_float(b);
}

// key = (sortable_value << 32) | ~idx  -> u64 max == (max value, then min idx)
__device__ __forceinline__ unsigned long long mkkey(uint32_t s, int idx) {
  return ((unsigned long long)s << 32) | (uint32_t)(~(uint32_t)idx);
}

// ---------- Threefry-2x32, key (0,1) [jax.random.key(1)], partitionable -----
// ks = [0, 1, 0x1BD11BDB]; counter (0, i); bits = out0 ^ out1.
__device__ __forceinline__ uint32_t rotl(uint32_t x, int r) {
  return (x << r) | (x >> (32 - r));
}
__device__ __forceinline__ uint32_t tf_bits(uint32_t i) {
  uint32_t x0 = 0u;
  uint32_t x1 = i + 1u;
#define R4(r0,r1,r2,r3) \
  x0 += x1; x1 = rotl(x1, r0); x1 ^= x0; \
  x0 += x1; x1 = rotl(x1, r1); x1 ^= x0; \
  x0 += x1; x1 = rotl(x1, r2); x1 ^= x0; \
  x0 += x1; x1 = rotl(x1, r3); x1 ^= x0;
  R4(13,15,26,6)
  x0 += 1u;            x1 += 0x1BD11BDBu + 1u;
  R4(17,29,16,24)
  x0 += 0x1BD11BDBu;   x1 += 0u + 2u;
  R4(13,15,26,6)
  /* x0 += 0 */        x1 += 1u + 3u;
  R4(17,29,16,24)
  x0 += 1u;            x1 += 0x1BD11BDBu + 4u;
  R4(13,15,26,6)
  x0 += 0x1BD11BDBu;   x1 += 0u + 5u;
#undef R4
  return x0 ^ x1;
}

// ---------- block reduce of u64-max (8 waves) -------------------------------
__device__ __forceinline__ unsigned long long blockMaxU64(unsigned long long v) {
  __shared__ unsigned long long s_w[NTHR / 64];
  const int wid = threadIdx.x >> 6, lane = threadIdx.x & 63;
  #pragma unroll
  for (int off = 32; off > 0; off >>= 1) {
    unsigned long long o = __shfl_xor(v, off, 64);
    if (o > v) v = o;
  }
  if (lane == 0) s_w[wid] = v;
  __syncthreads();
  if (threadIdx.x == 0) {
    #pragma unroll
    for (int w = 1; w < NTHR / 64; ++w) if (s_w[w] > v) v = s_w[w];
    s_w[0] = v;
  }
  __syncthreads();
  return s_w[0];
}

// ================== K1: per-quarter raw-logit max/argmax ====================
extern "C" __global__ void __launch_bounds__(NTHR, 4)
k1_rowmax(const float* __restrict__ logits,
          unsigned long long* __restrict__ partMax)
{
  const int blk = blockIdx.x;
  const int row = blk >> 2, q = blk & 3;
  const float4* base =
      reinterpret_cast<const float4*>(logits + (size_t)row * VCOLS + q * QCOLS);
  const int idx0 = q * QCOLS;

  unsigned long long best = 0ull;
  for (int vv = threadIdx.x; vv < QV4; vv += NTHR) {
    float4 l4 = base[vv];
    int v0 = idx0 + vv * 4;
    unsigned long long k0 = mkkey(fmap(l4.x), v0 + 0);
    unsigned long long k1 = mkkey(fmap(l4.y), v0 + 1);
    unsigned long long k2 = mkkey(fmap(l4.z), v0 + 2);
    unsigned long long k3 = mkkey(fmap(l4.w), v0 + 3);
    if (k1 > k0) k0 = k1;
    if (k3 > k2) k2 = k3;
    if (k2 > k0) k0 = k2;
    if (k0 > best) best = k0;
  }
  best = blockMaxU64(best);
  if (threadIdx.x == 0) partMax[blk] = best;
}

// ================== K2: per-quarter exponential-race argmax =================
extern "C" __global__ void __launch_bounds__(NTHR, 4)
k2_sample(const float* __restrict__ logits,
          const float* __restrict__ temps,
          const unsigned long long* __restrict__ partMax,
          unsigned long long* __restrict__ sampPart)
{
  const int blk = blockIdx.x;
  const int row = blk >> 2, q = blk & 3;
  const float4* base =
      reinterpret_cast<const float4*>(logits + (size_t)row * VCOLS + q * QCOLS);

  const float t = temps[row];
  const float safe_t = (t == 0.0f) ? 1.0f : t;
  const float inv_t = 1.0f / safe_t;

  // combine the row's four partials -> row max logit M; m = M * inv_t.
  // (max commutes with the monotone per-element map l -> l*inv_t, so m is
  //  bit-identical to max over per-element x values.)
  unsigned long long pm = partMax[row * 4];
  #pragma unroll
  for (int j = 1; j < 4; ++j) {
    unsigned long long o = partMax[row * 4 + j];
    if (o > pm) pm = o;
  }
  const float M = funmap((uint32_t)(pm >> 32));
  const float m = M * inv_t;

  const uint32_t flatbase = (uint32_t)row * (uint32_t)VCOLS + (uint32_t)(q * QCOLS);
  const int idx0 = q * QCOLS;

  unsigned long long best = 0ull;
  for (int vv = threadIdx.x; vv < QV4; vv += NTHR) {
    float4 l4 = base[vv];
    float lx[4] = {l4.x, l4.y, l4.z, l4.w};
    uint32_t i0 = flatbase + (uint32_t)(vv * 4);
    int v0 = idx0 + vv * 4;
    #pragma unroll
    for (int k = 0; k < 4; ++k) {
      uint32_t bits = tf_bits(i0 + (uint32_t)k);
      float f = __uint_as_float((bits >> 9) | 0x3F800000u);
      float u = f - 1.0f;
      float noise = -log1pf(-u);                  // +0.0 when bits>>9 == 0
      float x = lx[k] * inv_t;
      float e = __expf(x - m);                    // in [0,1]
      float ratio = e * __builtin_amdgcn_rcpf(noise); // inf when noise==0, NaN via 0*inf
      unsigned long long key = mkkey(__float_as_uint(ratio), v0 + k);
      if (key > best) best = key;
    }
  }
  best = blockMaxU64(best);
  if (threadIdx.x == 0) sampPart[blk] = best;
}

// ================== K3: combine quarters, greedy/sample select ==============
extern "C" __global__ void __launch_bounds__(BROWS)
k3_final(const float* __restrict__ temps,
         const unsigned long long* __restrict__ partMax,
         const unsigned long long* __restrict__ sampPart,
         int* __restrict__ out)
{
  const int r = threadIdx.x;
  if (r >= BROWS) return;
  unsigned long long g = partMax[r * 4];
  unsigned long long s = sampPart[r * 4];
  #pragma unroll
  for (int j = 1; j < 4; ++j) {
    unsigned long long og = partMax[r * 4 + j];
    unsigned long long os = sampPart[r * 4 + j];
    if (og > g) g = og;
    if (os > s) s = os;
  }
  const int greedy = (int)(~(uint32_t)g);
  const int samp   = (int)(~(uint32_t)s);
  out[r] = (temps[r] == 0.0f) ? greedy : samp;
}

extern "C" void kernel_launch(void* const* d_in, const int* in_sizes, int n_in,
                              void* d_out, int out_size, void* d_ws, size_t ws_size,
                              hipStream_t stream) {
  const float* logits = (const float*)d_in[0];
  const float* temps  = (const float*)d_in[1];
  int* out = (int*)d_out;

  unsigned long long* partMax  = (unsigned long long*)d_ws;            // NBLK entries
  unsigned long long* sampPart = partMax + NBLK;                       // NBLK entries

  k1_rowmax<<<NBLK, NTHR, 0, stream>>>(logits, partMax);
  k2_sample<<<NBLK, NTHR, 0, stream>>>(logits, temps, partMax, sampPart);
  k3_final<<<1, BROWS, 0, stream>>>(temps, partMax, sampPart, out);
}

// Round 4
// 109.778 us; speedup vs baseline: 2.4706x; 1.5618x over previous
//
#include <hip/hip_runtime.h>
#include <stdint.h>
#include <math.h>

constexpr int BROWS = 256;
constexpr int VCOLS = 128000;
constexpr int NQ    = 4;                 // quarter-rows
constexpr int QCOLS = VCOLS / NQ;        // 32000
constexpr int QV4   = QCOLS / 4;         // 8000 float4 per quarter
constexpr int NBLK  = BROWS * NQ;        // 1024 blocks
constexpr int NTHR  = 512;               // 8 waves per block

// ---------- sortable float <-> uint mapping (order-isomorphic) --------------
__device__ __forceinline__ uint32_t fmap(float v) {
  uint32_t b = __float_as_uint(v);
  return b ^ (uint32_t)(((int32_t)b >> 31) | 0x80000000);
}
__device__ __forceinline__ float funmap(uint32_t s) {
  uint32_t b = s ^ (uint32_t)(((~(int32_t)s) >> 31) | 0x80000000);
  return __uint_as_float(b);
}

// key = (sortable_value << 32) | ~idx  -> u64 max == (max value, then min idx)
__device__ __forceinline__ unsigned long long mkkey(uint32_t s, int idx) {
  return ((unsigned long long)s << 32) | (uint32_t)(~(uint32_t)idx);
}

// ---------- Threefry-2x32, key (0,1) [jax.random.key(1)], partitionable -----
// ks = [0, 1, 0x1BD11BDB]; counter (0, i); bits = out0 ^ out1.
__device__ __forceinline__ uint32_t rotl(uint32_t x, int r) {
  return (x << r) | (x >> (32 - r));
}
__device__ __forceinline__ uint32_t tf_bits(uint32_t i) {
  uint32_t x0 = 0u;
  uint32_t x1 = i + 1u;
#define R4(r0,r1,r2,r3) \
  x0 += x1; x1 = rotl(x1, r0); x1 ^= x0; \
  x0 += x1; x1 = rotl(x1, r1); x1 ^= x0; \
  x0 += x1; x1 = rotl(x1, r2); x1 ^= x0; \
  x0 += x1; x1 = rotl(x1, r3); x1 ^= x0;
  R4(13,15,26,6)
  x0 += 1u;            x1 += 0x1BD11BDBu + 1u;
  R4(17,29,16,24)
  x0 += 0x1BD11BDBu;   x1 += 0u + 2u;
  R4(13,15,26,6)
  /* x0 += 0 */        x1 += 1u + 3u;
  R4(17,29,16,24)
  x0 += 1u;            x1 += 0x1BD11BDBu + 4u;
  R4(13,15,26,6)
  x0 += 0x1BD11BDBu;   x1 += 0u + 5u;
#undef R4
  return x0 ^ x1;
}

// ---------- block reduce of u64-max (8 waves) -------------------------------
__device__ __forceinline__ unsigned long long blockMaxU64(unsigned long long v) {
  __shared__ unsigned long long s_w[NTHR / 64];
  const int wid = threadIdx.x >> 6, lane = threadIdx.x & 63;
  #pragma unroll
  for (int off = 32; off > 0; off >>= 1) {
    unsigned long long o = __shfl_xor(v, off, 64);
    if (o > v) v = o;
  }
  if (lane == 0) s_w[wid] = v;
  __syncthreads();
  if (threadIdx.x == 0) {
    #pragma unroll
    for (int w = 1; w < NTHR / 64; ++w) if (s_w[w] > v) v = s_w[w];
    s_w[0] = v;
  }
  __syncthreads();
  return s_w[0];
}

// ================== K1: per-quarter raw-logit max/argmax ====================
extern "C" __global__ void __launch_bounds__(NTHR, 4)
k1_rowmax(const float* __restrict__ logits,
          unsigned long long* __restrict__ partMax)
{
  const int blk = blockIdx.x;
  const int row = blk >> 2, q = blk & 3;
  const float4* base =
      reinterpret_cast<const float4*>(logits + (size_t)row * VCOLS + q * QCOLS);
  const int idx0 = q * QCOLS;

  unsigned long long best = 0ull;
  for (int vv = threadIdx.x; vv < QV4; vv += NTHR) {
    float4 l4 = base[vv];
    int v0 = idx0 + vv * 4;
    unsigned long long k0 = mkkey(fmap(l4.x), v0 + 0);
    unsigned long long k1 = mkkey(fmap(l4.y), v0 + 1);
    unsigned long long k2 = mkkey(fmap(l4.z), v0 + 2);
    unsigned long long k3 = mkkey(fmap(l4.w), v0 + 3);
    if (k1 > k0) k0 = k1;
    if (k3 > k2) k2 = k3;
    if (k2 > k0) k0 = k2;
    if (k0 > best) best = k0;
  }
  best = blockMaxU64(best);
  if (threadIdx.x == 0) partMax[blk] = best;
}

// ================== K2: per-quarter exponential-race argmax =================
extern "C" __global__ void __launch_bounds__(NTHR, 4)
k2_sample(const float* __restrict__ logits,
          const float* __restrict__ temps,
          const unsigned long long* __restrict__ partMax,
          unsigned long long* __restrict__ sampPart)
{
  const int blk = blockIdx.x;
  const int row = blk >> 2, q = blk & 3;
  const float4* base =
      reinterpret_cast<const float4*>(logits + (size_t)row * VCOLS + q * QCOLS);

  const float t = temps[row];
  const float safe_t = (t == 0.0f) ? 1.0f : t;
  const float inv_t = 1.0f / safe_t;

  // combine the row's four partials -> row max logit M; m = M * inv_t
  // (max commutes with the monotone map l -> l*inv_t).
  unsigned long long pm = partMax[row * 4];
  #pragma unroll
  for (int j = 1; j < 4; ++j) {
    unsigned long long o = partMax[row * 4 + j];
    if (o > pm) pm = o;
  }
  const float M = funmap((uint32_t)(pm >> 32));
  const float m = M * inv_t;

  const uint32_t flatbase = (uint32_t)row * (uint32_t)VCOLS + (uint32_t)(q * QCOLS);
  const int idx0 = q * QCOLS;

  unsigned long long best = 0ull;
  for (int vv = threadIdx.x; vv < QV4; vv += NTHR) {
    float4 l4 = base[vv];
    float lx[4] = {l4.x, l4.y, l4.z, l4.w};
    uint32_t i0 = flatbase + (uint32_t)(vv * 4);
    int v0 = idx0 + vv * 4;
    #pragma unroll
    for (int k = 0; k < 4; ++k) {
      uint32_t bits = tf_bits(i0 + (uint32_t)k);
      // f in [1,2); u = f-1 exact; 1-u = 2-f exact (Sterbenz).
      float f = __uint_as_float((bits >> 9) | 0x3F800000u);
      // noise = -log(1-u) = |log2(2-f)| * ln2  (native v_log_f32, ~1 ulp).
      // fabs makes the u==0 case give +0 (ratio -> +inf, matching reference).
      float noise = fabsf(__builtin_amdgcn_logf(2.0f - f) * 0.69314718055994531f);
      float x = lx[k] * inv_t;
      float e = __expf(x - m);                    // in [0,1]
      float ratio = e * __builtin_amdgcn_rcpf(noise); // inf when noise==0; 0*inf -> NaN
      unsigned long long key = mkkey(__float_as_uint(ratio), v0 + k);
      if (key > best) best = key;
    }
  }
  best = blockMaxU64(best);
  if (threadIdx.x == 0) sampPart[blk] = best;
}

// ================== K3: combine quarters, greedy/sample select ==============
extern "C" __global__ void __launch_bounds__(BROWS)
k3_final(const float* __restrict__ temps,
         const unsigned long long* __restrict__ partMax,
         const unsigned long long* __restrict__ sampPart,
         int* __restrict__ out)
{
  const int r = threadIdx.x;
  if (r >= BROWS) return;
  unsigned long long g = partMax[r * 4];
  unsigned long long s = sampPart[r * 4];
  #pragma unroll
  for (int j = 1; j < 4; ++j) {
    unsigned long long og = partMax[r * 4 + j];
    unsigned long long os = sampPart[r * 4 + j];
    if (og > g) g = og;
    if (os > s) s = os;
  }
  const int greedy = (int)(~(uint32_t)g);
  const int samp   = (int)(~(uint32_t)s);
  out[r] = (temps[r] == 0.0f) ? greedy : samp;
}

extern "C" void kernel_launch(void* const* d_in, const int* in_sizes, int n_in,
                              void* d_out, int out_size, void* d_ws, size_t ws_size,
                              hipStream_t stream) {
  const float* logits = (const float*)d_in[0];
  const float* temps  = (const float*)d_in[1];
  int* out = (int*)d_out;

  unsigned long long* partMax  = (unsigned long long*)d_ws;            // NBLK entries
  unsigned long long* sampPart = partMax + NBLK;                       // NBLK entries

  k1_rowmax<<<NBLK, NTHR, 0, stream>>>(logits, partMax);
  k2_sample<<<NBLK, NTHR, 0, stream>>>(logits, temps, partMax, sampPart);
  k3_final<<<1, BROWS, 0, stream>>>(temps, partMax, sampPart, out);
}

// Round 5
// 107.291 us; speedup vs baseline: 2.5278x; 1.0232x over previous
//
#include <hip/hip_runtime.h>
#include <stdint.h>
#include <math.h>

constexpr int BROWS = 256;
constexpr int VCOLS = 128000;
constexpr int NQ    = 4;                 // quarter-rows
constexpr int QCOLS = VCOLS / NQ;        // 32000
constexpr int QV4   = QCOLS / 4;         // 8000 float4 per quarter
constexpr int NBLK  = BROWS * NQ;        // 1024 blocks
constexpr int NTHR  = 512;               // 8 waves per block

// ---------- sortable float <-> uint mapping (order-isomorphic) --------------
__device__ __forceinline__ uint32_t fmap(float v) {
  uint32_t b = __float_as_uint(v);
  return b ^ (uint32_t)(((int32_t)b >> 31) | 0x80000000);
}
__device__ __forceinline__ float funmap(uint32_t s) {
  uint32_t b = s ^ (uint32_t)(((~(int32_t)s) >> 31) | 0x80000000);
  return __uint_as_float(b);
}

// key = (sortable_value << 32) | ~idx  -> u64 max == (max value, then min idx)
__device__ __forceinline__ unsigned long long mkkey(uint32_t s, int idx) {
  return ((unsigned long long)s << 32) | (uint32_t)(~(uint32_t)idx);
}

// ---------- Threefry-2x32, key (0,1) [jax.random.key(1)], partitionable -----
// ks = [0, 1, 0x1BD11BDB]; counter (0, i); bits = out0 ^ out1.
// rotl forced to v_alignbit_b32: alignbit(x,x,32-r) == rotl(x,r).
__device__ __forceinline__ uint32_t rotl(uint32_t x, uint32_t r) {
  return __builtin_amdgcn_alignbit(x, x, 32u - r);
}
// Takes x1_init = counter_lo + 1 (the first key-injection already applied).
__device__ __forceinline__ uint32_t tf_bits_x1(uint32_t x1i) {
  uint32_t x0 = 0u;
  uint32_t x1 = x1i;
#define R4(r0,r1,r2,r3) \
  x0 += x1; x1 = rotl(x1, r0); x1 ^= x0; \
  x0 += x1; x1 = rotl(x1, r1); x1 ^= x0; \
  x0 += x1; x1 = rotl(x1, r2); x1 ^= x0; \
  x0 += x1; x1 = rotl(x1, r3); x1 ^= x0;
  R4(13u,15u,26u,6u)
  x0 += 1u;            x1 += 0x1BD11BDBu + 1u;
  R4(17u,29u,16u,24u)
  x0 += 0x1BD11BDBu;   x1 += 0u + 2u;
  R4(13u,15u,26u,6u)
  /* x0 += 0 */        x1 += 1u + 3u;
  R4(17u,29u,16u,24u)
  x0 += 1u;            x1 += 0x1BD11BDBu + 4u;
  R4(13u,15u,26u,6u)
  x0 += 0x1BD11BDBu;   x1 += 0u + 5u;
#undef R4
  return x0 ^ x1;
}

// ---------- block reduce of u64-max (8 waves) -------------------------------
__device__ __forceinline__ unsigned long long blockMaxU64(unsigned long long v) {
  __shared__ unsigned long long s_w[NTHR / 64];
  const int wid = threadIdx.x >> 6, lane = threadIdx.x & 63;
  #pragma unroll
  for (int off = 32; off > 0; off >>= 1) {
    unsigned long long o = __shfl_xor(v, off, 64);
    if (o > v) v = o;
  }
  if (lane == 0) s_w[wid] = v;
  __syncthreads();
  if (threadIdx.x == 0) {
    #pragma unroll
    for (int w = 1; w < NTHR / 64; ++w) if (s_w[w] > v) v = s_w[w];
    s_w[0] = v;
  }
  __syncthreads();
  return s_w[0];
}

// ================== K1: per-quarter raw-logit max/argmax ====================
extern "C" __global__ void __launch_bounds__(NTHR, 4)
k1_rowmax(const float* __restrict__ logits,
          unsigned long long* __restrict__ partMax)
{
  const int blk = blockIdx.x;
  const int row = blk >> 2, q = blk & 3;
  const float4* base =
      reinterpret_cast<const float4*>(logits + (size_t)row * VCOLS + q * QCOLS);
  const int idx0 = q * QCOLS;

  unsigned long long best = 0ull;
  for (int vv = threadIdx.x; vv < QV4; vv += NTHR) {
    float4 l4 = base[vv];
    int v0 = idx0 + vv * 4;
    unsigned long long k0 = mkkey(fmap(l4.x), v0 + 0);
    unsigned long long k1 = mkkey(fmap(l4.y), v0 + 1);
    unsigned long long k2 = mkkey(fmap(l4.z), v0 + 2);
    unsigned long long k3 = mkkey(fmap(l4.w), v0 + 3);
    if (k1 > k0) k0 = k1;
    if (k3 > k2) k2 = k3;
    if (k2 > k0) k0 = k2;
    if (k0 > best) best = k0;
  }
  best = blockMaxU64(best);
  if (threadIdx.x == 0) partMax[blk] = best;
}

// ================== K2: per-quarter exponential-race argmax =================
// Log-domain: val = log2(p_unnorm/noise) = fma(l, c1, c0) - log2|log2(2-f)|
// with c1 = inv_t*log2e, c0 = -M*c1 - log2(ln2). Monotone in the ratio, so
// argmax matches; noise==0 (f==1.0) -> val=+inf; no NaN possible.
extern "C" __global__ void __launch_bounds__(NTHR, 4)
k2_sample(const float* __restrict__ logits,
          const float* __restrict__ temps,
          const unsigned long long* __restrict__ partMax,
          unsigned long long* __restrict__ sampPart)
{
  const int blk = blockIdx.x;
  const int row = blk >> 2, q = blk & 3;
  const float4* base =
      reinterpret_cast<const float4*>(logits + (size_t)row * VCOLS + q * QCOLS);

  const float t = temps[row];
  const float safe_t = (t == 0.0f) ? 1.0f : t;
  const float inv_t = 1.0f / safe_t;

  // combine the row's four partials -> row max logit M
  unsigned long long pm = partMax[row * 4];
  #pragma unroll
  for (int j = 1; j < 4; ++j) {
    unsigned long long o = partMax[row * 4 + j];
    if (o > pm) pm = o;
  }
  const float M = funmap((uint32_t)(pm >> 32));

  const float c1 = inv_t * 1.4426950408889634f;           // log2(e)/t
  const float c0 = fmaf(-M, c1, 0.5287663729448977f);     // -M*c1 - log2(ln2)

  const uint32_t rowbase = (uint32_t)row * (uint32_t)VCOLS;
  const uint32_t Ce = rowbase + (uint32_t)(q * QCOLS) + 1u; // counter + 1 base

  float bestv = -INFINITY;
  uint32_t bestx1 = 0u;

  for (int vv = threadIdx.x; vv < QV4; vv += NTHR) {
    float4 l4 = base[vv];
    const uint32_t ce = Ce + (uint32_t)(vv * 4);
    const float lx[4] = {l4.x, l4.y, l4.z, l4.w};
    #pragma unroll
    for (uint32_t k = 0; k < 4; ++k) {
      uint32_t x1i = ce + k;                       // == counter_lo + 1
      uint32_t bits = tf_bits_x1(x1i);
      // f in [1,2); 2-f exact (Sterbenz); g = log2(1-u); |g|*ln2 = noise.
      float f = __uint_as_float((bits >> 9) | 0x3F800000u);
      float g = __builtin_amdgcn_logf(2.0f - f);   // v_log_f32
      float ln_noise2 = __builtin_amdgcn_logf(fabsf(g)); // log2|g| (abs = free mod)
      float val = fmaf(lx[k], c1, c0) - ln_noise2; // +inf when g==0
      if (val > bestv) { bestv = val; bestx1 = x1i; }
    }
  }

  // recover column index within the row from the tracked x1-init
  const int colidx = (int)(bestx1 - 1u - rowbase);
  unsigned long long best = mkkey(fmap(bestv), colidx);
  best = blockMaxU64(best);
  if (threadIdx.x == 0) sampPart[blk] = best;
}

// ================== K3: combine quarters, greedy/sample select ==============
extern "C" __global__ void __launch_bounds__(BROWS)
k3_final(const float* __restrict__ temps,
         const unsigned long long* __restrict__ partMax,
         const unsigned long long* __restrict__ sampPart,
         int* __restrict__ out)
{
  const int r = threadIdx.x;
  if (r >= BROWS) return;
  unsigned long long g = partMax[r * 4];
  unsigned long long s = sampPart[r * 4];
  #pragma unroll
  for (int j = 1; j < 4; ++j) {
    unsigned long long og = partMax[r * 4 + j];
    unsigned long long os = sampPart[r * 4 + j];
    if (og > g) g = og;
    if (os > s) s = os;
  }
  const int greedy = (int)(~(uint32_t)g);
  const int samp   = (int)(~(uint32_t)s);
  out[r] = (temps[r] == 0.0f) ? greedy : samp;
}

extern "C" void kernel_launch(void* const* d_in, const int* in_sizes, int n_in,
                              void* d_out, int out_size, void* d_ws, size_t ws_size,
                              hipStream_t stream) {
  const float* logits = (const float*)d_in[0];
  const float* temps  = (const float*)d_in[1];
  int* out = (int*)d_out;

  unsigned long long* partMax  = (unsigned long long*)d_ws;            // NBLK entries
  unsigned long long* sampPart = partMax + NBLK;                       // NBLK entries

  k1_rowmax<<<NBLK, NTHR, 0, stream>>>(logits, partMax);
  k2_sample<<<NBLK, NTHR, 0, stream>>>(logits, temps, partMax, sampPart);
  k3_final<<<1, BROWS, 0, stream>>>(temps, partMax, sampPart, out);
}